// Round 4
// baseline (15600.069 us; speedup 1.0000x reference)
//
#include <hip/hip_runtime.h>

// HMM forward, B=64, T=1024, S=512, V=1024.
// Round 4: PAIR-SPLIT. Two blocks per batch (128 blocks x 256 threads); block
// h in {0,1} owns destination states h*256..h*256+255 and holds the matching
// half of E (u8, B-fragments, 128 AGPRs/wave, 4 waves). Per step each block:
//   quantize own half vs own HALF-max -> publish 256 bytes + half-max to
//   global (release flag) -> issue own-half MFMAs -> spin (acquire) for
//   partner -> partner-half MFMAs -> combine with 2 float weights (exact).
// Per-block MFMA phase halves (256->128 MFMAs, ~512 cyc); exchange overlaps
// own-half MFMAs. Flags zeroed by prep_scale each launch (graph-replay safe);
// pub slots ping-pong on t&1; pairs (b, b+64) share an XCD under round-robin.
// Precision: equal-or-better than round 0 (each half quantized vs a tighter max).

constexpr int Bn = 64, Tn = 1024, Sn = 512, HALF = 256;
#define L2E 1.44269504f

typedef int v4i __attribute__((ext_vector_type(4)));

#if __has_builtin(__builtin_amdgcn_update_dpp)
template <int CTRL>
__device__ __forceinline__ float dpp_fmax(float x) {
    int s = __builtin_bit_cast(int, x);
    int d = __builtin_amdgcn_update_dpp(s, s, CTRL, 0xf, 0xf, false);
    return fmaxf(x, __builtin_bit_cast(float, d));
}
__device__ __forceinline__ float wave_max64(float x) {
    x = dpp_fmax<0x121>(x);   // row_ror:1
    x = dpp_fmax<0x122>(x);   // row_ror:2
    x = dpp_fmax<0x124>(x);   // row_ror:4
    x = dpp_fmax<0x128>(x);   // row_ror:8
    x = dpp_fmax<0x142>(x);   // row_bcast:15
    x = dpp_fmax<0x143>(x);   // row_bcast:31
    return __builtin_bit_cast(float,
        __builtin_amdgcn_readlane(__builtin_bit_cast(int, x), 63));
}
#else
__device__ __forceinline__ float wave_max64(float x) {
    #pragma unroll
    for (int off = 32; off; off >>= 1) x = fmaxf(x, __shfl_xor(x, off, 64));
    return x;
}
#endif

// Eq value for (row i, col c) -> B-fragment byte address:
// frag = (c>>4)*8 + (i>>6); lane = ((i>>4)&3)*16 + (c&15); byte = i&15
__device__ __forceinline__ int bfrag_addr(int i, int c) {
    return ((((c >> 4) * 8 + (i >> 6)) * 64) + ((i >> 4) & 3) * 16 + (c & 15)) * 16
           + (i & 15);
}

// One block per row i: rowmax + quantize row to u8, scatter into B-frag layout.
__global__ __launch_bounds__(256) void prep_rows(
    const float* __restrict__ trans, unsigned char* __restrict__ EqB,
    float* __restrict__ rowmax)
{
    const int i = blockIdx.x;
    const int j = threadIdx.x;
    const int lane = j & 63, wv = j >> 6;
    float t0 = trans[i * Sn + j];
    float t1 = trans[i * Sn + j + 256];
    float m = fmaxf(t0, t1);
    #pragma unroll
    for (int off = 32; off; off >>= 1) m = fmaxf(m, __shfl_xor(m, off, 64));
    __shared__ float rm[4];
    if (lane == 0) rm[wv] = m;
    __syncthreads();
    m = fmaxf(fmaxf(rm[0], rm[1]), fmaxf(rm[2], rm[3]));
    if (j == 0) rowmax[i] = m;
    int q0 = __float2int_rn(127.f * __expf(t0 - m));
    int q1 = __float2int_rn(127.f * __expf(t1 - m));
    EqB[bfrag_addr(i, j)] = (unsigned char)q0;
    EqB[bfrag_addr(i, j + 256)] = (unsigned char)q1;
}

// lr[i] = log2(127 * exp(rowmax_i - RM)); C = RM - 2*ln(127). Also zero flags.
__global__ __launch_bounds__(512) void prep_scale(
    const float* __restrict__ rowmax, float* __restrict__ lr,
    float* __restrict__ Cp, unsigned* __restrict__ flags)
{
    const int i = threadIdx.x;
    const int lane = i & 63, wv = i >> 6;
    if (i < 256) flags[i] = 0u;          // stream-ordered before hmm_fwd_pair
    float m = rowmax[i];
    float rm = m;
    #pragma unroll
    for (int off = 32; off; off >>= 1) rm = fmaxf(rm, __shfl_xor(rm, off, 64));
    __shared__ float red[8];
    if (lane == 0) red[wv] = rm;
    __syncthreads();
    float RM = red[0];
    #pragma unroll
    for (int w = 1; w < 8; ++w) RM = fmaxf(RM, red[w]);
    lr[i] = (m - RM) * L2E + 6.98868469f;           // log2(127)
    if (i == 0) *Cp = RM - 9.68837417f;             // 2*ln(127)
}

__global__ __launch_bounds__(256, 2) void hmm_fwd_pair(
    const int* __restrict__ obs,          // [B, T]
    const float* __restrict__ emis,       // [V, S]
    const float* __restrict__ prior,      // [S]
    const v4i* __restrict__ EqB4,         // B-fragments, 16B per (frag,lane)
    const float* __restrict__ lr,         // [S]
    const float* __restrict__ Cp,         // scalar
    unsigned* __restrict__ flags,         // [64][2][2]
    unsigned char* __restrict__ pubB,     // [64][2][2][256]
    float* __restrict__ pubM,             // [64][2][2]
    float* __restrict__ hm,               // [64][2]
    float* __restrict__ hs)               // [64][2]
{
    const int bi = blockIdx.x;
    const int b  = bi & 63;               // batch
    const int h  = bi >> 6;               // half: 0 -> states 0..255, 1 -> 256..511
    const int ph = 1 - h;
    const int tid = threadIdx.x;          // 0..255; owns dest state j
    const int lane = tid & 63, wv = tid >> 6;   // wv in 0..3
    const int q = lane >> 4;
    const int j = h * HALF + tid;

    __shared__ int obs_s[Tn];
    __shared__ __align__(16) unsigned char Pq[Sn];   // full 512-byte P vector
    __shared__ __align__(16) float redm[4];
    __shared__ float reds[4];

    #pragma unroll
    for (int r = 0; r < 4; ++r) obs_s[tid + r * 256] = obs[b * Tn + tid + r * 256];

    // B-fragments for own 256 destinations: cols h*256 + wv*64 + tau*16 + (lane&15),
    // rows kap*64 + subchunks -> frag = (h*16 + wv*4 + tau)*8 + kap
    v4i Bf[4][8];
    #pragma unroll
    for (int tau = 0; tau < 4; ++tau)
        #pragma unroll
        for (int kap = 0; kap < 8; ++kap)
            Bf[tau][kap] = EqB4[(((h * 16 + wv * 4 + tau) * 8) + kap) * 64 + lane];

    const float lr_t = lr[j];
    const float C = *Cp;

    unsigned*       myFlag = flags + (b * 2 + h) * 2;
    unsigned*       paFlag = flags + (b * 2 + ph) * 2;
    unsigned char*  myPub  = pubB + (b * 2 + h) * 512;
    const unsigned char* paPub = pubB + (b * 2 + ph) * 512;
    float*          myPubM = pubM + (b * 2 + h) * 2;
    const float*    paPubM = pubM + (b * 2 + ph) * 2;

    __syncthreads();   // obs_s ready

    float a = emis[obs_s[0] * Sn + j] + prior[j];
    float e_next = emis[obs_s[1] * Sn + j];

    for (int t = 1; t < Tn; ++t) {
        const int par = t & 1;

        // ---- wave max, then 4-wave half-max via one LDS round trip
        float mw = wave_max64(a);
        if (lane == 0) redm[wv] = mw;
        __syncthreads();                         // A: redm ready; prev Af reads done
        float4 r4 = *(const float4*)redm;
        float mh = fmaxf(fmaxf(r4.x, r4.y), fmaxf(r4.z, r4.w));

        // ---- quantize own half vs half-max; stage to LDS + publish to global
        int gi = __float2int_rn(exp2f(fmaf(a - mh, L2E, lr_t)));
        Pq[h * HALF + tid] = (unsigned char)gi;
        myPub[par * 256 + tid] = (unsigned char)gi;
        if (tid == 0) myPubM[par] = mh;
        __threadfence();
        __syncthreads();                         // B: Pq own-half ready; pub fenced
        if (tid == 0)
            __hip_atomic_store(&myFlag[par], (unsigned)t,
                               __ATOMIC_RELEASE, __HIP_MEMORY_SCOPE_AGENT);

        float e_cur = e_next;
        if (t < Tn - 1) e_next = emis[obs_s[t + 1] * Sn + j];

        // ---- own-half A-frags + 16 MFMAs (kap = 4h..4h+3), chained per n-tile
        const unsigned char* Pb = Pq + q * 16;
        v4i AfO[4];
        #pragma unroll
        for (int k = 0; k < 4; ++k)
            AfO[k] = *(const v4i*)(Pb + (4 * h + k) * 64);
        v4i accO[4];
        #pragma unroll
        for (int tau = 0; tau < 4; ++tau) {
            v4i z = {0, 0, 0, 0};
            #pragma unroll
            for (int k = 0; k < 4; ++k)
                z = __builtin_amdgcn_mfma_i32_16x16x64_i8(AfO[k], Bf[tau][4 * h + k],
                                                          z, 0, 0, 0);
            accO[tau] = z;
        }

        // ---- spin for partner (acquire), then fetch its half
        while (__hip_atomic_load(&paFlag[par], __ATOMIC_ACQUIRE,
                                 __HIP_MEMORY_SCOPE_AGENT) != (unsigned)t) {}
        unsigned char pbyte = paPub[par * 256 + tid];
        float pm = paPubM[par];
        Pq[ph * HALF + tid] = pbyte;
        __syncthreads();                         // C: partner half staged

        v4i AfP[4];
        #pragma unroll
        for (int k = 0; k < 4; ++k)
            AfP[k] = *(const v4i*)(Pb + (4 * ph + k) * 64);
        v4i accP[4];
        #pragma unroll
        for (int tau = 0; tau < 4; ++tau) {
            v4i z = {0, 0, 0, 0};
            #pragma unroll
            for (int k = 0; k < 4; ++k)
                z = __builtin_amdgcn_mfma_i32_16x16x64_i8(AfP[k], Bf[tau][4 * ph + k],
                                                          z, 0, 0, 0);
            accP[tau] = z;
        }

        // ---- exact 2-group combine (one weight is 1.0)
        float mp = fmaxf(mh, pm);
        float wO = exp2f((mh - mp) * L2E);
        float wP = exp2f((pm - mp) * L2E);

        int dO = (lane < 16) ? accO[0].x
               : (lane < 32) ? accO[1].x
               : (lane < 48) ? accO[2].x
                             : accO[3].x;
        int dP = (lane < 16) ? accP[0].x
               : (lane < 32) ? accP[1].x
               : (lane < 48) ? accP[2].x
                             : accP[3].x;

        float d = fmaf(wO, (float)dO, wP * (float)dP);
        a = e_cur + mp + C + __logf(d);
    }

    // ---- half logsumexp -> hm/hs; combined by hmm_finish
    float m = wave_max64(a);
    if (lane == 0) redm[wv] = m;
    __syncthreads();
    float4 r4 = *(const float4*)redm;
    m = fmaxf(fmaxf(r4.x, r4.y), fmaxf(r4.z, r4.w));

    float s = __expf(a - m);
    #pragma unroll
    for (int off = 32; off; off >>= 1) s += __shfl_xor(s, off, 64);
    if (lane == 0) reds[wv] = s;
    __syncthreads();
    if (tid == 0) {
        hm[b * 2 + h] = m;
        hs[b * 2 + h] = reds[0] + reds[1] + reds[2] + reds[3];
    }
}

__global__ __launch_bounds__(64) void hmm_finish(
    const float* __restrict__ hm, const float* __restrict__ hs,
    float* __restrict__ out)
{
    const int b = threadIdx.x;
    float l0 = hm[b * 2 + 0] + __logf(hs[b * 2 + 0]);
    float l1 = hm[b * 2 + 1] + __logf(hs[b * 2 + 1]);
    float mx = fmaxf(l0, l1);
    out[b] = mx + __logf(__expf(l0 - mx) + __expf(l1 - mx));
}

extern "C" void kernel_launch(void* const* d_in, const int* in_sizes, int n_in,
                              void* d_out, int out_size, void* d_ws, size_t ws_size,
                              hipStream_t stream) {
    const int*   obs   = (const int*)d_in[0];
    const float* emis  = (const float*)d_in[1];
    const float* trans = (const float*)d_in[2];
    const float* prior = (const float*)d_in[3];
    float* out = (float*)d_out;

    unsigned char* EqB = (unsigned char*)d_ws;                 // 256 KB
    float* rowmax = (float*)(EqB + Sn * Sn);                   // 512 f
    float* lr     = rowmax + Sn;                               // 512 f
    float* Cp     = lr + Sn;                                   // 1 f
    unsigned* flags = (unsigned*)(Cp + 1);                     // 256 u32
    unsigned char* pubB = (unsigned char*)(flags + 256);       // 64 KB
    float* pubM = (float*)(pubB + 64 * 2 * 2 * 256);           // 256 f
    float* hm = pubM + 256;                                    // 128 f
    float* hs = hm + 128;                                      // 128 f

    prep_rows<<<Sn, 256, 0, stream>>>(trans, EqB, rowmax);
    prep_scale<<<1, Sn, 0, stream>>>(rowmax, lr, Cp, flags);
    hmm_fwd_pair<<<128, 256, 0, stream>>>(obs, emis, prior,
                                          (const v4i*)EqB, lr, Cp,
                                          flags, pubB, pubM, hm, hs);
    hmm_finish<<<1, 64, 0, stream>>>(hm, hs, out);
}

// Round 6
// 987.057 us; speedup vs baseline: 15.8046x; 15.8046x over previous
//
#include <hip/hip_runtime.h>

// HMM forward, B=64, T=1024, S=512, V=1024.
// Round 6 (resubmit of round 5; infra failure, kernel never ran):
// revert to the proven round-0 structure (957 us) + ring micro-shaves.
// One block per batch. E = exp(trans) quantized u8 (per-row scale folded into
// P's quantization) as MFMA B-fragments in registers (128 VGPRs).
// Inner product: v_mfma_i32_16x16x64_i8 with ALL 16 A-rows identical
// (quad-broadcast reads of the linear P byte vector) -> every C row is the
// result -> thread reads acc[lane>>4].x in-register. 2 barriers/step, exact
// global max, chained accumulators (proven fastest variant).
// Shaves vs round-0: (1) post-B1 reduce via 2x b128 broadcast reads + 7-fmax
// tree (was b32 read + 3 dependent DPP); (2) obs_s[Tn] pad removes the
// per-step t<Tn-1 branch on the e_next prefetch.

constexpr int Bn = 64, Tn = 1024, Sn = 512;
#define L2E 1.44269504f

typedef int v4i __attribute__((ext_vector_type(4)));

#if __has_builtin(__builtin_amdgcn_update_dpp)
template <int CTRL>
__device__ __forceinline__ float dpp_fmax(float x) {
    int s = __builtin_bit_cast(int, x);
    int d = __builtin_amdgcn_update_dpp(s, s, CTRL, 0xf, 0xf, false);
    return fmaxf(x, __builtin_bit_cast(float, d));
}
__device__ __forceinline__ float wave_max64(float x) {
    x = dpp_fmax<0x121>(x);   // row_ror:1
    x = dpp_fmax<0x122>(x);   // row_ror:2
    x = dpp_fmax<0x124>(x);   // row_ror:4
    x = dpp_fmax<0x128>(x);   // row_ror:8
    x = dpp_fmax<0x142>(x);   // row_bcast:15
    x = dpp_fmax<0x143>(x);   // row_bcast:31
    return __builtin_bit_cast(float,
        __builtin_amdgcn_readlane(__builtin_bit_cast(int, x), 63));
}
#else
__device__ __forceinline__ float wave_max64(float x) {
    #pragma unroll
    for (int off = 32; off; off >>= 1) x = fmaxf(x, __shfl_xor(x, off, 64));
    return x;
}
#endif

// Eq value for (row i, col c) -> B-fragment byte address:
// frag = (c>>4)*8 + (i>>6); lane = ((i>>4)&3)*16 + (c&15); byte = i&15
__device__ __forceinline__ int bfrag_addr(int i, int c) {
    return ((((c >> 4) * 8 + (i >> 6)) * 64) + ((i >> 4) & 3) * 16 + (c & 15)) * 16
           + (i & 15);
}

// One block per row i: rowmax + quantize row to u8, scatter into B-frag layout.
__global__ __launch_bounds__(256) void prep_rows(
    const float* __restrict__ trans, unsigned char* __restrict__ EqB,
    float* __restrict__ rowmax)
{
    const int i = blockIdx.x;
    const int j = threadIdx.x;
    const int lane = j & 63, wv = j >> 6;
    float t0 = trans[i * Sn + j];
    float t1 = trans[i * Sn + j + 256];
    float m = fmaxf(t0, t1);
    #pragma unroll
    for (int off = 32; off; off >>= 1) m = fmaxf(m, __shfl_xor(m, off, 64));
    __shared__ float rm[4];
    if (lane == 0) rm[wv] = m;
    __syncthreads();
    m = fmaxf(fmaxf(rm[0], rm[1]), fmaxf(rm[2], rm[3]));
    if (j == 0) rowmax[i] = m;
    int q0 = __float2int_rn(127.f * __expf(t0 - m));
    int q1 = __float2int_rn(127.f * __expf(t1 - m));
    EqB[bfrag_addr(i, j)] = (unsigned char)q0;
    EqB[bfrag_addr(i, j + 256)] = (unsigned char)q1;
}

// lr[i] = log2(127 * exp(rowmax_i - RM)); C = RM - 2*ln(127)
__global__ __launch_bounds__(512) void prep_scale(
    const float* __restrict__ rowmax, float* __restrict__ lr,
    float* __restrict__ Cp)
{
    const int i = threadIdx.x;
    const int lane = i & 63, wv = i >> 6;
    float m = rowmax[i];
    float rm = m;
    #pragma unroll
    for (int off = 32; off; off >>= 1) rm = fmaxf(rm, __shfl_xor(rm, off, 64));
    __shared__ float red[8];
    if (lane == 0) red[wv] = rm;
    __syncthreads();
    float RM = red[0];
    #pragma unroll
    for (int w = 1; w < 8; ++w) RM = fmaxf(RM, red[w]);
    lr[i] = (m - RM) * L2E + 6.98868469f;           // log2(127)
    if (i == 0) *Cp = RM - 9.68837417f;             // 2*ln(127)
}

__global__ __launch_bounds__(512, 2) void hmm_fwd(
    const int* __restrict__ obs,          // [B, T]
    const float* __restrict__ emis,       // [V, S]
    const float* __restrict__ prior,      // [S]
    const v4i* __restrict__ EqB4,         // B-fragments, 16B per (frag,lane)
    const float* __restrict__ lr,         // [S]
    const float* __restrict__ Cp,         // scalar
    float* __restrict__ out)              // [B]
{
    const int b = blockIdx.x;
    const int tid = threadIdx.x;          // state j owned by this thread
    const int lane = tid & 63, wv = tid >> 6;
    const int q = lane >> 4;

    __shared__ int obs_s[Tn + 1];
    __shared__ __align__(16) unsigned char Pq[2][Sn];
    __shared__ __align__(16) float redm[2][8];
    __shared__ float reds[8];

    int o0 = obs[b * Tn + tid];
    int o1 = obs[b * Tn + 512 + tid];
    obs_s[tid] = o0;
    obs_s[tid + 512] = o1;
    if (tid == 511) obs_s[Tn] = o1;       // pad: makes e_next prefetch branch-free

    // B-fragments: Bf[tau][kap] = E rows kap*64+(16k-subchunks), cols wv*64+tau*16+(lane&15)
    v4i Bf[4][8];
    #pragma unroll
    for (int tau = 0; tau < 4; ++tau)
        #pragma unroll
        for (int kap = 0; kap < 8; ++kap)
            Bf[tau][kap] = EqB4[((wv * 4 + tau) * 8 + kap) * 64 + lane];

    const float lr_t = lr[tid];
    const float C = *Cp;

    __syncthreads();   // obs_s ready

    float a = emis[obs_s[0] * Sn + tid] + prior[tid];
    float e_next = emis[obs_s[1] * Sn + tid];

    for (int t = 1; t < Tn; ++t) {
        const int pb = t & 1;

        // ---- exact block max: DPP in-wave, one LDS round-trip cross-wave
        float mw = wave_max64(a);
        if (lane == 0) redm[pb][wv] = mw;
        __syncthreads();                          // barrier 1
        // broadcast b128 reads (issued back-to-back) + 7-fmax tree
        float4 r0 = *(const float4*)&redm[pb][0];
        float4 r1 = *(const float4*)&redm[pb][4];
        float m = fmaxf(fmaxf(fmaxf(r0.x, r0.y), fmaxf(r0.z, r0.w)),
                        fmaxf(fmaxf(r1.x, r1.y), fmaxf(r1.z, r1.w)));

        // ---- quantize P (u8, row-scale folded) into linear byte vector
        int gi = __float2int_rn(exp2f(fmaf(a - m, L2E, lr_t)));
        Pq[pb][tid] = (unsigned char)gi;
        __syncthreads();                          // barrier 2

        float e_cur = e_next;
        e_next = emis[obs_s[t + 1] * Sn + tid];   // branch-free (obs_s[Tn] pad)

        // ---- A-fragments: quad-broadcast reads of P (all 16 A-rows identical)
        const unsigned char* Pbase = Pq[pb] + q * 16;
        v4i Af[8];
        #pragma unroll
        for (int kap = 0; kap < 8; ++kap)
            Af[kap] = *(const v4i*)(Pbase + kap * 64);

        // ---- 4 n-tiles x 8 k-chunks of mfma_i32_16x16x64_i8
        v4i acc[4];
        #pragma unroll
        for (int tau = 0; tau < 4; ++tau) {
            v4i z = {0, 0, 0, 0};
            #pragma unroll
            for (int kap = 0; kap < 8; ++kap)
                z = __builtin_amdgcn_mfma_i32_16x16x64_i8(Af[kap], Bf[tau][kap],
                                                          z, 0, 0, 0);
            acc[tau] = z;
        }

        // ---- every C row equals the result: select tau = lane>>4 in-register
        int idot = (lane < 16) ? acc[0].x
                 : (lane < 32) ? acc[1].x
                 : (lane < 48) ? acc[2].x
                               : acc[3].x;

        a = e_cur + m + C + __logf((float)idot);
    }

    // ---- out[b] = logsumexp_j(alpha[j])
    float m = a;
    #pragma unroll
    for (int off = 32; off; off >>= 1) m = fmaxf(m, __shfl_xor(m, off, 64));
    if (lane == 0) redm[0][wv] = m;
    __syncthreads();
    #pragma unroll
    for (int w = 0; w < 8; ++w) m = fmaxf(m, redm[0][w]);

    float s = __expf(a - m);
    #pragma unroll
    for (int off = 32; off; off >>= 1) s += __shfl_xor(s, off, 64);
    if (lane == 0) reds[wv] = s;
    __syncthreads();
    if (tid == 0) {
        float tot = 0.f;
        #pragma unroll
        for (int w = 0; w < 8; ++w) tot += reds[w];
        out[b] = m + __logf(tot);
    }
}

extern "C" void kernel_launch(void* const* d_in, const int* in_sizes, int n_in,
                              void* d_out, int out_size, void* d_ws, size_t ws_size,
                              hipStream_t stream) {
    const int*   obs   = (const int*)d_in[0];
    const float* emis  = (const float*)d_in[1];
    const float* trans = (const float*)d_in[2];
    const float* prior = (const float*)d_in[3];
    float* out = (float*)d_out;

    unsigned char* EqB = (unsigned char*)d_ws;                // 256 KB
    float* rowmax = (float*)(EqB + Sn * Sn);                  // 2 KB
    float* lr     = rowmax + Sn;                              // 2 KB
    float* Cp     = lr + Sn;                                  // 4 B

    prep_rows<<<Sn, 256, 0, stream>>>(trans, EqB, rowmax);
    prep_scale<<<1, Sn, 0, stream>>>(rowmax, lr, Cp);
    hmm_fwd<<<Bn, Sn, 0, stream>>>(obs, emis, prior,
                                   (const v4i*)EqB, lr, Cp, out);
}

// Round 7
// 962.476 us; speedup vs baseline: 16.2083x; 1.0255x over previous
//
#include <hip/hip_runtime.h>

// HMM forward, B=64, T=1024, S=512, V=1024.
// Round 7: round-6 structure (941 us measured) with the EXP-DOMAIN ring.
// The per-step log/exp round-trip cancels algebraically:
//   a_j = S + ln(wd_j)  (S block-uniform scalar, tracked off-path)
//   q_j = round(lrf_j * wd_j / W),  W = block max of wd,  lrf_j = 127*2^lr_j
//   wd'_j = exp(e_j) * idot_j      (exp(e_j) computed off-path at prefetch)
//   S'    = S + ln W + C           (consumed only by the final lse)
// Critical path per step: select -> cvt -> mul -> DPP max -> LDS/barrier ->
// 7-fmax -> rcp -> mul -> round -> Pq write -> barrier -> Af -> MFMA.
// No logf/exp2f/fmaf on the ring. Math identical up to f32 rounding.

constexpr int Bn = 64, Tn = 1024, Sn = 512;
#define L2E 1.44269504f

typedef int v4i __attribute__((ext_vector_type(4)));

#if __has_builtin(__builtin_amdgcn_update_dpp)
template <int CTRL>
__device__ __forceinline__ float dpp_fmax(float x) {
    int s = __builtin_bit_cast(int, x);
    int d = __builtin_amdgcn_update_dpp(s, s, CTRL, 0xf, 0xf, false);
    return fmaxf(x, __builtin_bit_cast(float, d));
}
__device__ __forceinline__ float wave_max64(float x) {
    x = dpp_fmax<0x121>(x);   // row_ror:1
    x = dpp_fmax<0x122>(x);   // row_ror:2
    x = dpp_fmax<0x124>(x);   // row_ror:4
    x = dpp_fmax<0x128>(x);   // row_ror:8
    x = dpp_fmax<0x142>(x);   // row_bcast:15
    x = dpp_fmax<0x143>(x);   // row_bcast:31
    return __builtin_bit_cast(float,
        __builtin_amdgcn_readlane(__builtin_bit_cast(int, x), 63));
}
#else
__device__ __forceinline__ float wave_max64(float x) {
    #pragma unroll
    for (int off = 32; off; off >>= 1) x = fmaxf(x, __shfl_xor(x, off, 64));
    return x;
}
#endif

// Eq value for (row i, col c) -> B-fragment byte address:
// frag = (c>>4)*8 + (i>>6); lane = ((i>>4)&3)*16 + (c&15); byte = i&15
__device__ __forceinline__ int bfrag_addr(int i, int c) {
    return ((((c >> 4) * 8 + (i >> 6)) * 64) + ((i >> 4) & 3) * 16 + (c & 15)) * 16
           + (i & 15);
}

// One block per row i: rowmax + quantize row to u8, scatter into B-frag layout.
__global__ __launch_bounds__(256) void prep_rows(
    const float* __restrict__ trans, unsigned char* __restrict__ EqB,
    float* __restrict__ rowmax)
{
    const int i = blockIdx.x;
    const int j = threadIdx.x;
    const int lane = j & 63, wv = j >> 6;
    float t0 = trans[i * Sn + j];
    float t1 = trans[i * Sn + j + 256];
    float m = fmaxf(t0, t1);
    #pragma unroll
    for (int off = 32; off; off >>= 1) m = fmaxf(m, __shfl_xor(m, off, 64));
    __shared__ float rm[4];
    if (lane == 0) rm[wv] = m;
    __syncthreads();
    m = fmaxf(fmaxf(rm[0], rm[1]), fmaxf(rm[2], rm[3]));
    if (j == 0) rowmax[i] = m;
    int q0 = __float2int_rn(127.f * __expf(t0 - m));
    int q1 = __float2int_rn(127.f * __expf(t1 - m));
    EqB[bfrag_addr(i, j)] = (unsigned char)q0;
    EqB[bfrag_addr(i, j + 256)] = (unsigned char)q1;
}

// lr[i] = log2(127 * exp(rowmax_i - RM)); C = RM - 2*ln(127)
__global__ __launch_bounds__(512) void prep_scale(
    const float* __restrict__ rowmax, float* __restrict__ lr,
    float* __restrict__ Cp)
{
    const int i = threadIdx.x;
    const int lane = i & 63, wv = i >> 6;
    float m = rowmax[i];
    float rm = m;
    #pragma unroll
    for (int off = 32; off; off >>= 1) rm = fmaxf(rm, __shfl_xor(rm, off, 64));
    __shared__ float red[8];
    if (lane == 0) red[wv] = rm;
    __syncthreads();
    float RM = red[0];
    #pragma unroll
    for (int w = 1; w < 8; ++w) RM = fmaxf(RM, red[w]);
    lr[i] = (m - RM) * L2E + 6.98868469f;           // log2(127)
    if (i == 0) *Cp = RM - 9.68837417f;             // 2*ln(127)
}

__global__ __launch_bounds__(512, 2) void hmm_fwd(
    const int* __restrict__ obs,          // [B, T]
    const float* __restrict__ emis,       // [V, S]
    const float* __restrict__ prior,      // [S]
    const v4i* __restrict__ EqB4,         // B-fragments, 16B per (frag,lane)
    const float* __restrict__ lr,         // [S]
    const float* __restrict__ Cp,         // scalar
    float* __restrict__ out)              // [B]
{
    const int b = blockIdx.x;
    const int tid = threadIdx.x;          // state j owned by this thread
    const int lane = tid & 63, wv = tid >> 6;
    const int q = lane >> 4;

    __shared__ int obs_s[Tn + 1];
    __shared__ __align__(16) unsigned char Pq[2][Sn];
    __shared__ __align__(16) float redm[2][8];
    __shared__ float reds[8];

    int o0 = obs[b * Tn + tid];
    int o1 = obs[b * Tn + 512 + tid];
    obs_s[tid] = o0;
    obs_s[tid + 512] = o1;
    if (tid == 511) obs_s[Tn] = o1;       // pad: branch-free e prefetch

    // B-fragments: Bf[tau][kap] = E rows kap*64+(16k-subchunks), cols wv*64+tau*16+(lane&15)
    v4i Bf[4][8];
    #pragma unroll
    for (int tau = 0; tau < 4; ++tau)
        #pragma unroll
        for (int kap = 0; kap < 8; ++kap)
            Bf[tau][kap] = EqB4[((wv * 4 + tau) * 8 + kap) * 64 + lane];

    const float lrf = exp2f(lr[tid]);     // 127 * exp(rowmax_j - RM), <= 127
    const float C = *Cp;

    __syncthreads();   // obs_s ready

    // alpha_0 in exp form: a_j = S + ln(wd_j), S = 0
    float a0 = emis[obs_s[0] * Sn + tid] + prior[tid];
    float wd = __expf(a0);
    float lw = lrf * wd;
    float S = 0.f;
    float eN = emis[obs_s[1] * Sn + tid];   // raw e for step 1

    for (int t = 1; t < Tn; ++t) {
        const int pb = t & 1;

        // ---- exact block max of wd: DPP in-wave, one LDS round-trip cross-wave
        float mw = wave_max64(wd);
        if (lane == 0) redm[pb][wv] = mw;
        __syncthreads();                          // barrier 1
        float4 r0 = *(const float4*)&redm[pb][0];
        float4 r1 = *(const float4*)&redm[pb][4];
        float W = fmaxf(fmaxf(fmaxf(r0.x, r0.y), fmaxf(r0.z, r0.w)),
                        fmaxf(fmaxf(r1.x, r1.y), fmaxf(r1.z, r1.w)));

        float weC = __expf(eN);                   // off-path (TRANS pipe)

        // ---- quantize: q = round(lrf * wd / W)  (== 127*2^lr*exp(a - m'))
        float rw = __builtin_amdgcn_rcpf(W);
        int gi = __float2int_rn(lw * rw);
        Pq[pb][tid] = (unsigned char)gi;
        __syncthreads();                          // barrier 2

        S += __logf(W) + C;                       // off-path scalar accumulate
        eN = emis[obs_s[t + 1] * Sn + tid];       // raw e prefetch for t+1

        // ---- A-fragments: quad-broadcast reads of P (all 16 A-rows identical)
        const unsigned char* Pbase = Pq[pb] + q * 16;
        v4i Af[8];
        #pragma unroll
        for (int kap = 0; kap < 8; ++kap)
            Af[kap] = *(const v4i*)(Pbase + kap * 64);

        // ---- 4 n-tiles x 8 k-chunks of mfma_i32_16x16x64_i8
        v4i acc[4];
        #pragma unroll
        for (int tau = 0; tau < 4; ++tau) {
            v4i z = {0, 0, 0, 0};
            #pragma unroll
            for (int kap = 0; kap < 8; ++kap)
                z = __builtin_amdgcn_mfma_i32_16x16x64_i8(Af[kap], Bf[tau][kap],
                                                          z, 0, 0, 0);
            acc[tau] = z;
        }

        // ---- every C row equals the result: select tau = lane>>4 in-register
        int idot = (lane < 16) ? acc[0].x
                 : (lane < 32) ? acc[1].x
                 : (lane < 48) ? acc[2].x
                               : acc[3].x;

        // ---- alpha update in exp form (no log on the ring)
        float df = (float)idot;
        wd = weC * df;
        lw = lrf * wd;
    }

    // ---- out[b] = S + ln(sum_j wd_j)  via max-normalized sum
    float mw = wave_max64(wd);
    if (lane == 0) redm[0][wv] = mw;
    __syncthreads();
    float Wf = mw;
    #pragma unroll
    for (int w = 0; w < 8; ++w) Wf = fmaxf(Wf, redm[0][w]);

    float s = wd * __builtin_amdgcn_rcpf(Wf);
    #pragma unroll
    for (int off = 32; off; off >>= 1) s += __shfl_xor(s, off, 64);
    if (lane == 0) reds[wv] = s;
    __syncthreads();
    if (tid == 0) {
        float tot = 0.f;
        #pragma unroll
        for (int w = 0; w < 8; ++w) tot += reds[w];
        out[b] = S + __logf(Wf) + __logf(tot);
    }
}

extern "C" void kernel_launch(void* const* d_in, const int* in_sizes, int n_in,
                              void* d_out, int out_size, void* d_ws, size_t ws_size,
                              hipStream_t stream) {
    const int*   obs   = (const int*)d_in[0];
    const float* emis  = (const float*)d_in[1];
    const float* trans = (const float*)d_in[2];
    const float* prior = (const float*)d_in[3];
    float* out = (float*)d_out;

    unsigned char* EqB = (unsigned char*)d_ws;                // 256 KB
    float* rowmax = (float*)(EqB + Sn * Sn);                  // 2 KB
    float* lr     = rowmax + Sn;                              // 2 KB
    float* Cp     = lr + Sn;                                  // 4 B

    prep_rows<<<Sn, 256, 0, stream>>>(trans, EqB, rowmax);
    prep_scale<<<1, Sn, 0, stream>>>(rowmax, lr, Cp);
    hmm_fwd<<<Bn, Sn, 0, stream>>>(obs, emis, prior,
                                   (const v4i*)EqB, lr, Cp, out);
}